// Round 5
// baseline (3260.709 us; speedup 1.0000x reference)
//
#include <hip/hip_runtime.h>

// SeqAutoEncoder on MI355X.  B=64, T=2048, D=256, H=30, G=4H=120, NOUT=5.
//   K1 gemm_pre : pre1 = seq @ enc_W1[0:256] + enc_b1   (parallel, 8 GFLOP fp32)
//   K2 scan     : 33 blocks x 1 wave, TWO chains per wave (A=lanes 0-31, B=32-63).
//                 In-lane gates: lane r owns unit r's (i,j,f,o) -> no shfl.
//                 float2 packed accs -> v_pk_fma; weights pinned in VGPRs via asm.
//                 h broadcast through LDS (same-wave, in-order DS, no barriers).
//                 Iter s computes L1(s) and L2(s-1), parity-buffered h in LDS.
//                 chains: blk*2+ch; chain 64 = decoder (zero input), 65 = inactive.
//   K3 bcast    : dec_out[b,t] = dec_seq[t]
// ws: pre1 [64*2048*120] f32 (62.9 MB), then dec_seq [2048] f32.
//
// R3 post-mortem: single wave was 77% issue-bound at ~575 instr/step; VGPR=104
// proves weights were NOT register-resident (compiler re-loaded per step).
// This version: ~90 pk-FMA + ~8 LDS-read + ~26 act instr per chain-step.

#define BB 64
#define TT 2048
#define DD 256
#define HH 30
#define GG 120
#define PRE_ELEMS (64u * 2048u * 120u)

typedef float f32x2 __attribute__((ext_vector_type(2)));
typedef float f32x4 __attribute__((ext_vector_type(4)));

#define L2E 1.442695040888963f
__device__ __forceinline__ float fast_exp2(float x) { return __builtin_amdgcn_exp2f(x); }
__device__ __forceinline__ float fast_rcp(float x) { return __builtin_amdgcn_rcpf(x); }
// EXACT same formulas as the R2/R3 passing kernels (absmax 0.0)
__device__ __forceinline__ float sigm_(float x) {
  return fast_rcp(1.0f + fast_exp2(x * -L2E));
}
__device__ __forceinline__ float tanh_(float x) {
  return 1.0f - 2.0f * fast_rcp(1.0f + fast_exp2(2.0f * L2E * x));
}

// ---------------- K1: pre1 = seq @ Wx1 + b1 ---------------- (unchanged)
__global__ __launch_bounds__(256) void gemm_pre(const float* __restrict__ A,
                                                const float* __restrict__ W,
                                                const float* __restrict__ bias,
                                                float* __restrict__ out) {
  __shared__ __align__(16) float sA[32 * 132];
  __shared__ __align__(16) float sW[32 * 120];
  const int tid = threadIdx.x;
  const int row0 = blockIdx.x * 128;
  const int tx = tid % 30;
  const int ty = tid / 30;
  const bool comp = tid < 240;
  float4 acc[16];
#pragma unroll
  for (int i = 0; i < 16; ++i) acc[i] = make_float4(0.f, 0.f, 0.f, 0.f);
  const float4* A4 = (const float4*)A;
  const float4* W4 = (const float4*)W;
  const int rload = tid >> 3;
  const int kq = tid & 7;
  for (int k0 = 0; k0 < 256; k0 += 32) {
    __syncthreads();
#pragma unroll
    for (int it = 0; it < 4; ++it) {
      int idx = tid + it * 256;
      if (idx < 960) ((float4*)sW)[idx] = W4[k0 * 30 + idx];
    }
#pragma unroll
    for (int m = 0; m < 4; ++m) {
      int rr = rload + m * 32;
      float4 v = A4[(size_t)(row0 + rr) * 64 + (k0 >> 2) + kq];
      int kk = kq * 4;
      sA[(kk + 0) * 132 + rr] = v.x;
      sA[(kk + 1) * 132 + rr] = v.y;
      sA[(kk + 2) * 132 + rr] = v.z;
      sA[(kk + 3) * 132 + rr] = v.w;
    }
    __syncthreads();
    if (comp) {
#pragma unroll 4
      for (int k = 0; k < 32; ++k) {
        const float4 w = ((const float4*)sW)[k * 30 + tx];
        const float4* a4 = (const float4*)&sA[k * 132 + ty * 16];
        float4 a0 = a4[0], a1 = a4[1], a2 = a4[2], a3 = a4[3];
        float av[16] = {a0.x, a0.y, a0.z, a0.w, a1.x, a1.y, a1.z, a1.w,
                        a2.x, a2.y, a2.z, a2.w, a3.x, a3.y, a3.z, a3.w};
#pragma unroll
        for (int i = 0; i < 16; ++i) {
          acc[i].x = fmaf(av[i], w.x, acc[i].x);
          acc[i].y = fmaf(av[i], w.y, acc[i].y);
          acc[i].z = fmaf(av[i], w.z, acc[i].z);
          acc[i].w = fmaf(av[i], w.w, acc[i].w);
        }
      }
    }
  }
  if (comp) {
    const float4 bv = ((const float4*)bias)[tx];
#pragma unroll
    for (int i = 0; i < 16; ++i) {
      int row = row0 + ty * 16 + i;
      float4 r;
      r.x = acc[i].x + bv.x;
      r.y = acc[i].y + bv.y;
      r.z = acc[i].z + bv.z;
      r.w = acc[i].w + bv.w;
      ((float4*)out)[(size_t)row * 30 + tx] = r;
    }
  }
}

// ---------------- K2: 2-chains-per-wave fused scan ----------------
__global__ __launch_bounds__(64, 1) void scan_kernel(
    const float* __restrict__ pre, const float* __restrict__ enc_W1,
    const float* __restrict__ enc_W2, const float* __restrict__ enc_b2,
    const float* __restrict__ enc_Wd, const float* __restrict__ enc_bd,
    const float* __restrict__ dec_W1, const float* __restrict__ dec_b1,
    const float* __restrict__ dec_W2, const float* __restrict__ dec_b2,
    float* __restrict__ out, float* __restrict__ dec_seq) {
  // [parity][chain-half][layer][unit(pad 32)]
  __shared__ __align__(16) float hlds[2][2][2][32];
  const int lane = threadIdx.x;
  const int ch = lane >> 5;       // 0 = chain A, 1 = chain B
  const int rw = lane & 31;       // LDS slot (30,31 = pad, written but never read)
  const int rc = (rw < 30) ? rw : 0;  // column alias for loads (keeps all addrs in-bounds)
  const int chain = blockIdx.x * 2 + ch;   // 0..65
  const bool isdec = (chain == BB);        // chain 64
  const bool live_enc = (chain < BB);
  // zero LDS (single wave: DS ops in-order, no barrier needed)
  ((float*)hlds)[lane] = 0.f;
  ((float*)hlds)[lane + 64] = 0.f;
  ((float*)hlds)[lane + 128] = 0.f;
  ((float*)hlds)[lane + 192] = 0.f;

  // ---- per-lane weights: unit rc's 4 gate columns, packed (i,j) / (f,o) ----
  f32x2 w1ij[30], w1fo[30], w2ij[60], w2fo[60];
  {
    const float* W1h = isdec ? (dec_W1 + GG) : (enc_W1 + (size_t)DD * GG);
#pragma unroll
    for (int k = 0; k < 30; ++k) {
      const float* row = W1h + k * GG;
      w1ij[k] = {row[rc], row[30 + rc]};
      w1fo[k] = {row[60 + rc], row[90 + rc]};
    }
    const float* W2 = isdec ? dec_W2 : enc_W2;
#pragma unroll
    for (int k = 0; k < 60; ++k) {
      const float* row = W2 + k * GG;
      w2ij[k] = {row[rc], row[30 + rc]};
      w2fo[k] = {row[60 + rc], row[90 + rc]};
    }
  }
  // pin weights in VGPRs: blocks rematerialization-from-memory (R3's failure mode)
#pragma unroll
  for (int k = 0; k < 30; ++k) asm volatile("" : "+v"(w1ij[k]), "+v"(w1fo[k]));
#pragma unroll
  for (int k = 0; k < 60; ++k) asm volatile("" : "+v"(w2ij[k]), "+v"(w2fo[k]));

  const float* b2p = isdec ? dec_b2 : enc_b2;
  f32x2 b2ij = {b2p[rc], b2p[30 + rc]};
  f32x2 b2fo = {b2p[60 + rc], b2p[90 + rc]};
  f32x2 dIJ = {dec_b1[rc], dec_b1[30 + rc]};
  f32x2 dFO = {dec_b1[60 + rc], dec_b1[90 + rc]};
  asm volatile("" : "+v"(b2ij), "+v"(b2fo), "+v"(dIJ), "+v"(dFO));

  // L1 input term stream: encoder reads pre1 (bias included); dec = const dec_b1.
  const int cclamp = live_enc ? chain : 0;  // dec/inactive read chain0 (blended/unused)
  const float* prbase = pre + (size_t)cclamp * TT * GG + rc;

  float c1, c2 = 0.f, h1v;
  // ---- peel: L1(0), h1(-1)=0, c1(-1)=0 ----
  f32x2 pcIJ, pcFO, pnIJ, pnFO;
  {
    f32x2 r0IJ = {prbase[0], prbase[30]};
    f32x2 r0FO = {prbase[60], prbase[90]};
    pcIJ = {prbase[GG + 0], prbase[GG + 30]};
    pcFO = {prbase[GG + 60], prbase[GG + 90]};
    pnIJ = {prbase[2 * GG + 0], prbase[2 * GG + 30]};
    pnFO = {prbase[2 * GG + 60], prbase[2 * GG + 90]};
    if (isdec) { r0IJ = dIJ; r0FO = dFO; }
    float i_s = sigm_(r0IJ.x);
    float j_t = tanh_(r0IJ.y);
    float f_s = sigm_(r0FO.x + 1.0f);
    float o_s = sigm_(r0FO.y);
    c1 = i_s * j_t;
    h1v = tanh_(c1) * o_s;
    hlds[0][ch][0][rw] = h1v;
  }
  const float* prow = prbase + 3 * GG;  // next load target: row s+2 at s=1
  const bool do_dec = (blockIdx.x == 32) && (lane == HH - 1);

  // ---- main loop: iter s computes L1(s) and L2(s-1) ----
  for (int s = 1; s < TT; ++s) {
    const int p = s & 1, q = p ^ 1;
    // h1(s-1) [parity q], broadcast read (all lanes of a half read same addrs)
    f32x4 h1a[8];
#pragma unroll
    for (int u = 0; u < 8; ++u) h1a[u] = ((const f32x4*)&hlds[q][ch][0][0])[u];
    // prefetch pre row s+2 (depth-2; harmless tail overrun stays inside ws)
    f32x2 ldIJ = {prow[0], prow[30]};
    f32x2 ldFO = {prow[60], prow[90]};
    prow += GG;
    f32x2 a1 = isdec ? dIJ : pcIJ;   // L1(s) preacts (input term incl. bias)
    f32x2 a2 = isdec ? dFO : pcFO;
    f32x2 bb1 = b2ij, bb2 = b2fo;    // L2(s-1) preacts
#pragma unroll
    for (int k = 0; k < 30; ++k) {
      float hk = h1a[k >> 2][k & 3];
      f32x2 hh = {hk, hk};
      a1 += w1ij[k] * hh;
      a2 += w1fo[k] * hh;
      bb1 += w2ij[k] * hh;
      bb2 += w2fo[k] * hh;
    }
    // h2(s-2) [parity p] read after first FMA block (shorter live range)
    f32x4 h2a[8];
#pragma unroll
    for (int u = 0; u < 8; ++u) h2a[u] = ((const f32x4*)&hlds[p][ch][1][0])[u];
#pragma unroll
    for (int k = 0; k < 30; ++k) {
      float hk = h2a[k >> 2][k & 3];
      f32x2 hh = {hk, hk};
      bb1 += w2ij[30 + k] * hh;
      bb2 += w2fo[30 + k] * hh;
    }
    // L1(s) tail -> h1(s), all in-lane
    {
      float i_s = sigm_(a1.x), j_t = tanh_(a1.y);
      float f_s = sigm_(a2.x + 1.0f), o_s = sigm_(a2.y);
      c1 = fmaf(c1, f_s, i_s * j_t);
      h1v = tanh_(c1) * o_s;
      hlds[p][ch][0][rw] = h1v;
    }
    // L2(s-1) tail -> h2(s-1)
    {
      float i_s = sigm_(bb1.x), j_t = tanh_(bb1.y);
      float f_s = sigm_(bb2.x + 1.0f), o_s = sigm_(bb2.y);
      c2 = fmaf(c2, f_s, i_s * j_t);
      float h2v = tanh_(c2) * o_s;
      hlds[q][ch][1][rw] = h2v;
      if (do_dec) dec_seq[s - 1] = h2v;
    }
    pcIJ = pnIJ; pcFO = pnFO; pnIJ = ldIJ; pnFO = ldFO;
  }

  // ---- epilogue: L2(TT-1)  (s = TT: p=0, q=1) ----
  {
    f32x4 h1a[8], h2a[8];
#pragma unroll
    for (int u = 0; u < 8; ++u) h1a[u] = ((const f32x4*)&hlds[1][ch][0][0])[u];
#pragma unroll
    for (int u = 0; u < 8; ++u) h2a[u] = ((const f32x4*)&hlds[0][ch][1][0])[u];
    f32x2 bb1 = b2ij, bb2 = b2fo;
#pragma unroll
    for (int k = 0; k < 30; ++k) {
      float hk = h1a[k >> 2][k & 3];
      f32x2 hh = {hk, hk};
      bb1 += w2ij[k] * hh;
      bb2 += w2fo[k] * hh;
    }
#pragma unroll
    for (int k = 0; k < 30; ++k) {
      float hk = h2a[k >> 2][k & 3];
      f32x2 hh = {hk, hk};
      bb1 += w2ij[30 + k] * hh;
      bb2 += w2fo[30 + k] * hh;
    }
    float i_s = sigm_(bb1.x), j_t = tanh_(bb1.y);
    float f_s = sigm_(bb2.x + 1.0f), o_s = sigm_(bb2.y);
    c2 = fmaf(c2, f_s, i_s * j_t);
    float h2fin = tanh_(c2) * o_s;
    if (do_dec) dec_seq[TT - 1] = h2fin;
    // latent = tanh(h2(TT-1) @ enc_Wd + enc_bd), via LDS re-broadcast
    hlds[0][ch][1][rw] = h2fin;
    const int jc = (rw < 5) ? rw : 0;
    float a = enc_bd[jc];
#pragma unroll
    for (int k = 0; k < 30; ++k) a = fmaf(hlds[0][ch][1][k], enc_Wd[k * 5 + jc], a);
    if (rw < 5 && live_enc) out[BB * TT + chain * 5 + rw] = tanh_(a);
  }
}

// ---------------- K3: broadcast decoder chain to all batch rows ----------------
__global__ __launch_bounds__(256) void bcast_kernel(const float* __restrict__ dec_seq,
                                                    float* __restrict__ out) {
  int i4 = blockIdx.x * 256 + threadIdx.x;  // 32768 float4s
  ((float4*)out)[i4] = ((const float4*)dec_seq)[i4 & (TT / 4 - 1)];
}

extern "C" void kernel_launch(void* const* d_in, const int* in_sizes, int n_in,
                              void* d_out, int out_size, void* d_ws, size_t ws_size,
                              hipStream_t stream) {
  const float* seq = (const float*)d_in[0];
  const float* enc_W1 = (const float*)d_in[1];
  const float* enc_b1 = (const float*)d_in[2];
  const float* enc_W2 = (const float*)d_in[3];
  const float* enc_b2 = (const float*)d_in[4];
  const float* enc_Wd = (const float*)d_in[5];
  const float* enc_bd = (const float*)d_in[6];
  // d_in[7] dec_Wd, d_in[8] dec_bd: dead code in reference (vec2 unused)
  const float* dec_W1 = (const float*)d_in[9];
  const float* dec_b1 = (const float*)d_in[10];
  const float* dec_W2 = (const float*)d_in[11];
  const float* dec_b2 = (const float*)d_in[12];
  float* out = (float*)d_out;
  float* pre = (float*)d_ws;         // 62.9 MB
  float* dec_seq = pre + PRE_ELEMS;  // 8 KB

  gemm_pre<<<dim3(1024), dim3(256), 0, stream>>>(seq, enc_W1, enc_b1, pre);
  scan_kernel<<<dim3(33), dim3(64), 0, stream>>>(pre, enc_W1, enc_W2, enc_b2,
                                                 enc_Wd, enc_bd, dec_W1, dec_b1,
                                                 dec_W2, dec_b2, out, dec_seq);
  bcast_kernel<<<dim3(128), dim3(256), 0, stream>>>(dec_seq, out);
}

// Round 6
// 1225.086 us; speedup vs baseline: 2.6616x; 2.6616x over previous
//
#include <hip/hip_runtime.h>

// SeqAutoEncoder on MI355X.  B=64, T=2048, D=256, H=30, G=4H=120, NOUT=5.
//   K1 gemm_pre : pre1 = seq @ enc_W1[0:256] + enc_b1   (parallel, 8 GFLOP fp32)
//   K2 scan     : 65 blocks x 2 waves (wave0=L1, wave1=L2), segment-pipelined:
//                 segment g: wave0 does L1(2g,2g+1), wave1 does L2(2g-2,2g-1).
//                 h1 passed through a 4-slot LDS ring; raw s_barrier with
//                 lgkmcnt-only wait (NO vmcnt drain -> global prefetch of pre1
//                 stays in flight across barriers; R2's __syncthreads drained
//                 it every step = the hidden 2x).
//                 Weights register-resident: wave0 60 floats, wave1 120 floats
//                 per lane (fits 256-VGPR budget; R4's 360 could not).
//   K3 bcast    : dec_out[b,t] = dec_seq[t]
// ws: pre1 [64*2048*120] f32 (62.9 MB), then dec_seq [2048] f32.
//
// Lane map (proven exact in R3, absmax 0.0): lanes 0..29 own (i,f) cols of
// unit r=lane; lanes 32..61 own (j,o) cols of unit r=lane-32. Uniform
// activation p1 = fma(rcp(1+exp2(m1*x)), A1, B1) folds sigm/tanh, no branch.
// Cross-gate exchange = one shfl_xor(32) pair.

#define BB 64
#define TT 2048
#define DD 256
#define HH 30
#define GG 120
#define PRE_ELEMS (64u * 2048u * 120u)

typedef float f32x4 __attribute__((ext_vector_type(4)));

#define L2E 1.442695040888963f
__device__ __forceinline__ float fast_exp2(float x) { return __builtin_amdgcn_exp2f(x); }
__device__ __forceinline__ float fast_rcp(float x) { return __builtin_amdgcn_rcpf(x); }
__device__ __forceinline__ float tanh_(float x) {
  // (e^2x - 1)/(e^2x + 1); exp2 overflow -> inf -> rcp -> 0 -> +/-1 correct
  return 1.0f - 2.0f * fast_rcp(1.0f + fast_exp2(2.0f * L2E * x));
}

// ---------------- K1: pre1 = seq @ Wx1 + b1 ---------------- (unchanged)
__global__ __launch_bounds__(256) void gemm_pre(const float* __restrict__ A,
                                                const float* __restrict__ W,
                                                const float* __restrict__ bias,
                                                float* __restrict__ out) {
  __shared__ __align__(16) float sA[32 * 132];
  __shared__ __align__(16) float sW[32 * 120];
  const int tid = threadIdx.x;
  const int row0 = blockIdx.x * 128;
  const int tx = tid % 30;
  const int ty = tid / 30;
  const bool comp = tid < 240;
  float4 acc[16];
#pragma unroll
  for (int i = 0; i < 16; ++i) acc[i] = make_float4(0.f, 0.f, 0.f, 0.f);
  const float4* A4 = (const float4*)A;
  const float4* W4 = (const float4*)W;
  const int rload = tid >> 3;
  const int kq = tid & 7;
  for (int k0 = 0; k0 < 256; k0 += 32) {
    __syncthreads();
#pragma unroll
    for (int it = 0; it < 4; ++it) {
      int idx = tid + it * 256;
      if (idx < 960) ((float4*)sW)[idx] = W4[k0 * 30 + idx];
    }
#pragma unroll
    for (int m = 0; m < 4; ++m) {
      int rr = rload + m * 32;
      float4 v = A4[(size_t)(row0 + rr) * 64 + (k0 >> 2) + kq];
      int kk = kq * 4;
      sA[(kk + 0) * 132 + rr] = v.x;
      sA[(kk + 1) * 132 + rr] = v.y;
      sA[(kk + 2) * 132 + rr] = v.z;
      sA[(kk + 3) * 132 + rr] = v.w;
    }
    __syncthreads();
    if (comp) {
#pragma unroll 4
      for (int k = 0; k < 32; ++k) {
        const float4 w = ((const float4*)sW)[k * 30 + tx];
        const float4* a4 = (const float4*)&sA[k * 132 + ty * 16];
        float4 a0 = a4[0], a1 = a4[1], a2 = a4[2], a3 = a4[3];
        float av[16] = {a0.x, a0.y, a0.z, a0.w, a1.x, a1.y, a1.z, a1.w,
                        a2.x, a2.y, a2.z, a2.w, a3.x, a3.y, a3.z, a3.w};
#pragma unroll
        for (int i = 0; i < 16; ++i) {
          acc[i].x = fmaf(av[i], w.x, acc[i].x);
          acc[i].y = fmaf(av[i], w.y, acc[i].y);
          acc[i].z = fmaf(av[i], w.z, acc[i].z);
          acc[i].w = fmaf(av[i], w.w, acc[i].w);
        }
      }
    }
  }
  if (comp) {
    const float4 bv = ((const float4*)bias)[tx];
#pragma unroll
    for (int i = 0; i < 16; ++i) {
      int row = row0 + ty * 16 + i;
      float4 r;
      r.x = acc[i].x + bv.x;
      r.y = acc[i].y + bv.y;
      r.z = acc[i].z + bv.z;
      r.w = acc[i].w + bv.w;
      ((float4*)out)[(size_t)row * 30 + tx] = r;
    }
  }
}

// ---------------- K2: 2-wave segment-pipelined fused scan ----------------
__global__ __launch_bounds__(128, 1) void scan_kernel(
    const float* __restrict__ pre, const float* __restrict__ enc_W1,
    const float* __restrict__ enc_W2, const float* __restrict__ enc_b2,
    const float* __restrict__ enc_Wd, const float* __restrict__ enc_bd,
    const float* __restrict__ dec_W1, const float* __restrict__ dec_b1,
    const float* __restrict__ dec_W2, const float* __restrict__ dec_b2,
    float* __restrict__ out, float* __restrict__ dec_seq) {
  __shared__ __align__(16) float ring[4][32];  // h1(t) -> slot t&3
  __shared__ __align__(16) float h2b[32];      // wave1-private h2 broadcast buf
  const int tid = threadIdx.x;
  const int wave = tid >> 6;
  const int lane = tid & 63;
  const int blk = blockIdx.x;
  const bool isdec = (blk == BB);
  const int r = lane & 31;
  const bool jo = lane >= 32;
  const int cA = (r < 30) ? (jo ? 30 + r : r) : 0;  // i or j col (idle lanes alias 0)
  const int cB = cA + 60;                           // f or o col
  const float m1 = jo ? 2.0f * L2E : -L2E;
  const float A1 = jo ? -2.0f : 1.0f;
  const float B1 = jo ? 1.0f : 0.0f;
  const float fb = jo ? 0.0f : 1.0f;
  const bool wlane = lane < 30;
  const bool do_dec = isdec && (lane == HH - 1);

  // ---- register-resident weights (wave0: W1 hidden rows; wave1: W2) ----
  float wA[60], wB[60];
  if (wave == 0) {
    const float* W1h = isdec ? (dec_W1 + GG) : (enc_W1 + (size_t)DD * GG);
#pragma unroll
    for (int k = 0; k < 30; ++k) {
      wA[k] = W1h[k * GG + cA];
      wB[k] = W1h[k * GG + cB];
    }
#pragma unroll
    for (int k = 30; k < 60; ++k) {
      wA[k] = 0.f;
      wB[k] = 0.f;
    }
  } else {
    const float* W2 = isdec ? dec_W2 : enc_W2;
#pragma unroll
    for (int k = 0; k < 60; ++k) {
      wA[k] = W2[k * GG + cA];
      wB[k] = W2[k * GG + cB];
    }
  }
#pragma unroll
  for (int k = 0; k < 60; ++k) asm volatile("" : "+v"(wA[k]), "+v"(wB[k]));

  const float* b2p = isdec ? dec_b2 : enc_b2;
  const float b2A = b2p[cA], b2B = b2p[cB];
  const float db1A = dec_b1[cA], db1B = dec_b1[cB];

  const int cb = (blk < BB) ? blk : 0;  // dec block streams chain0 rows (unused)
  const float* pr = pre + (size_t)cb * TT * GG;

  f32x4 h1a[8], h2a[8];
#pragma unroll
  for (int u = 0; u < 8; ++u) {
    h1a[u] = f32x4{0.f, 0.f, 0.f, 0.f};
    h2a[u] = f32x4{0.f, 0.f, 0.f, 0.f};
  }
  float c1 = 0.f, c2 = 0.f;

  // wave0: L1 step t. Consumes h1(t-1) (already in h1a), writes h1(t) to ring,
  // reads it back (same-wave in-order DS) for the next step.
  auto l1step = [&](int t, float pA, float pB) {
    float aA = isdec ? db1A : pA;
    float aB = isdec ? db1B : pB;
#pragma unroll
    for (int k = 0; k < 30; ++k) {
      float hk = h1a[k >> 2][k & 3];
      aA = fmaf(hk, wA[k], aA);
      aB = fmaf(hk, wB[k], aB);
    }
    float t1 = fast_rcp(1.0f + fast_exp2(aA * m1));
    float p1 = fmaf(t1, A1, B1);               // sigm(i) / tanh(j)
    float p2 = fast_rcp(1.0f + fast_exp2((aB + fb) * -L2E));  // sigm(f+1) / sigm(o)
    float jv = __shfl_xor(p1, 32, 64);
    float ov = __shfl_xor(p2, 32, 64);
    c1 = fmaf(c1, p2, p1 * jv);
    float hv = tanh_(c1) * ov;
    if (wlane) ring[t & 3][lane] = hv;
#pragma unroll
    for (int u = 0; u < 8; ++u) h1a[u] = ((const f32x4*)&ring[t & 3][0])[u];
  };

  // wave1: L2 step t. Reads h1(t) from ring (valid: written last segment),
  // h2(t-1) from h2a. Accumulation order = reference (bias, h1 rows, h2 rows).
  auto l2step = [&](int t) {
#pragma unroll
    for (int u = 0; u < 8; ++u) h1a[u] = ((const f32x4*)&ring[t & 3][0])[u];
    float aA = b2A, aB = b2B;
#pragma unroll
    for (int k = 0; k < 30; ++k) {
      float hk = h1a[k >> 2][k & 3];
      aA = fmaf(hk, wA[k], aA);
      aB = fmaf(hk, wB[k], aB);
    }
#pragma unroll
    for (int k = 0; k < 30; ++k) {
      float hk = h2a[k >> 2][k & 3];
      aA = fmaf(hk, wA[30 + k], aA);
      aB = fmaf(hk, wB[30 + k], aB);
    }
    float t1 = fast_rcp(1.0f + fast_exp2(aA * m1));
    float p1 = fmaf(t1, A1, B1);
    float p2 = fast_rcp(1.0f + fast_exp2((aB + fb) * -L2E));
    float jv = __shfl_xor(p1, 32, 64);
    float ov = __shfl_xor(p2, 32, 64);
    c2 = fmaf(c2, p2, p1 * jv);
    float hv = tanh_(c2) * ov;
    if (do_dec) dec_seq[t] = hv;
    if (wlane) h2b[lane] = hv;
#pragma unroll
    for (int u = 0; u < 8; ++u) h2a[u] = ((const f32x4*)&h2b[0])[u];
  };

  // pre1 prefetch queue: rows (2g,2g+1) current, (2g+2,2g+3) next; loads for
  // (2g+4,2g+5) issued each segment -> 2 segments (~2x400cyc) of latency slack.
  float qA0 = pr[0 * GG + cA], qB0 = pr[0 * GG + cB];
  float qA1 = pr[1 * GG + cA], qB1 = pr[1 * GG + cB];
  float rA0 = pr[2 * GG + cA], rB0 = pr[2 * GG + cB];
  float rA1 = pr[3 * GG + cA], rB1 = pr[3 * GG + cB];

  for (int g = 0; g < TT / 2; ++g) {
    if (wave == 0) {
      int tp0 = (2 * g + 4 < TT) ? 2 * g + 4 : 0;  // clamp: tail loads discarded
      int tp1 = (2 * g + 5 < TT) ? 2 * g + 5 : 0;
      float fA0 = pr[(size_t)tp0 * GG + cA], fB0 = pr[(size_t)tp0 * GG + cB];
      float fA1 = pr[(size_t)tp1 * GG + cA], fB1 = pr[(size_t)tp1 * GG + cB];
      l1step(2 * g, qA0, qB0);
      l1step(2 * g + 1, qA1, qB1);
      qA0 = rA0; qB0 = rB0; qA1 = rA1; qB1 = rB1;
      rA0 = fA0; rB0 = fB0; rA1 = fA1; rB1 = fB1;
    } else if (g > 0) {
      l2step(2 * g - 2);
      l2step(2 * g - 1);
    }
    // raw barrier: lgkmcnt(0) makes own LDS writes visible; NO vmcnt drain,
    // so the global pre1 prefetch stays in flight across the barrier.
    asm volatile("s_waitcnt lgkmcnt(0)\n\ts_barrier" ::: "memory");
  }

  // tail: L2(2046), L2(2047) (ring slots written in final segment, visible
  // after last barrier); then latent / final dec store.
  if (wave == 1) {
    l2step(TT - 2);
    l2step(TT - 1);
    if (!isdec) {
      // latent = tanh(h2(T-1) @ enc_Wd + enc_bd); h2(T-1) already broadcast in h2a
      const int jc = (lane < 5) ? lane : 0;
      float a = enc_bd[jc];
#pragma unroll
      for (int k = 0; k < 30; ++k)
        a = fmaf(h2a[k >> 2][k & 3], enc_Wd[k * 5 + jc], a);
      if (lane < 5) out[BB * TT + blk * 5 + lane] = tanh_(a);
    }
  }
}

// ---------------- K3: broadcast decoder chain to all batch rows ----------------
__global__ __launch_bounds__(256) void bcast_kernel(const float* __restrict__ dec_seq,
                                                    float* __restrict__ out) {
  int i4 = blockIdx.x * 256 + threadIdx.x;  // 32768 float4s
  ((float4*)out)[i4] = ((const float4*)dec_seq)[i4 & (TT / 4 - 1)];
}

extern "C" void kernel_launch(void* const* d_in, const int* in_sizes, int n_in,
                              void* d_out, int out_size, void* d_ws, size_t ws_size,
                              hipStream_t stream) {
  const float* seq = (const float*)d_in[0];
  const float* enc_W1 = (const float*)d_in[1];
  const float* enc_b1 = (const float*)d_in[2];
  const float* enc_W2 = (const float*)d_in[3];
  const float* enc_b2 = (const float*)d_in[4];
  const float* enc_Wd = (const float*)d_in[5];
  const float* enc_bd = (const float*)d_in[6];
  // d_in[7] dec_Wd, d_in[8] dec_bd: dead code in reference (vec2 unused)
  const float* dec_W1 = (const float*)d_in[9];
  const float* dec_b1 = (const float*)d_in[10];
  const float* dec_W2 = (const float*)d_in[11];
  const float* dec_b2 = (const float*)d_in[12];
  float* out = (float*)d_out;
  float* pre = (float*)d_ws;         // 62.9 MB
  float* dec_seq = pre + PRE_ELEMS;  // 8 KB

  gemm_pre<<<dim3(1024), dim3(256), 0, stream>>>(seq, enc_W1, enc_b1, pre);
  scan_kernel<<<dim3(65), dim3(128), 0, stream>>>(pre, enc_W1, enc_W2, enc_b2,
                                                  enc_Wd, enc_bd, dec_W1, dec_b1,
                                                  dec_W2, dec_b2, out, dec_seq);
  bcast_kernel<<<dim3(128), dim3(256), 0, stream>>>(dec_seq, out);
}

// Round 12
// 1177.701 us; speedup vs baseline: 2.7687x; 1.0402x over previous
//
#include <hip/hip_runtime.h>

// SeqAutoEncoder on MI355X.  B=64, T=2048, D=256, H=30, G=4H=120, NOUT=5.
//   K1 gemm_pre : pre1 = seq @ enc_W1[0:256] + enc_b1   (parallel, 8 GFLOP fp32)
//   K2 scan     : 65 blocks x 2 waves (wave0=L1, wave1=L2), segment-pipelined:
//                 segment g: wave0 does L1(2g,2g+1), wave1 does L2(2g-2,2g-1).
//                 h1 crosses waves through a 4-slot LDS ring; SELF-broadcast of
//                 h (wave0:h1, wave1:h2) via v_readlane -> SGPR (no LDS
//                 round-trip, frees 32 VGPRs each). Raw s_barrier with
//                 lgkmcnt-only wait (global pre1 prefetch stays in flight).
//                 amdgpu_waves_per_eu(1,1): stops the allocator from
//                 rematerializing the 120 weight loads per step (R3/R5/R6
//                 failure mode: VGPR_Count=108 < 120 weights needed).
//   K3 bcast    : dec_out[b,t] = dec_seq[t]
// ws: pre1 [64*2048*120] f32 (62.9 MB), then dec_seq [2048] f32.
//
// Lane map (proven exact, absmax 0.0 since R3): lanes 0..29 own (i,f) cols of
// unit r=lane; lanes 32..61 own (j,o) cols of unit r=lane-32. Uniform
// activation p1 = fma(rcp(1+exp2(m1*x)), A1, B1) folds sigm/tanh, no branch.
// Cross-gate exchange = one shfl_xor(32) pair. Accumulation order = reference
// (bias, h1 rows ascending, h2 rows ascending) -> bit-exact.

#define BB 64
#define TT 2048
#define DD 256
#define HH 30
#define GG 120
#define PRE_ELEMS (64u * 2048u * 120u)

typedef float f32x4 __attribute__((ext_vector_type(4)));

#define L2E 1.442695040888963f
__device__ __forceinline__ float fast_exp2(float x) { return __builtin_amdgcn_exp2f(x); }
__device__ __forceinline__ float fast_rcp(float x) { return __builtin_amdgcn_rcpf(x); }
__device__ __forceinline__ float tanh_(float x) {
  // (e^2x - 1)/(e^2x + 1); exp2 overflow -> inf -> rcp -> 0 -> +/-1 correct
  return 1.0f - 2.0f * fast_rcp(1.0f + fast_exp2(2.0f * L2E * x));
}
__device__ __forceinline__ float bcastf(float v, int l) {
  return __builtin_bit_cast(float,
                            __builtin_amdgcn_readlane(__builtin_bit_cast(int, v), l));
}

// ---------------- K1: pre1 = seq @ Wx1 + b1 ---------------- (unchanged)
__global__ __launch_bounds__(256) void gemm_pre(const float* __restrict__ A,
                                                const float* __restrict__ W,
                                                const float* __restrict__ bias,
                                                float* __restrict__ out) {
  __shared__ __align__(16) float sA[32 * 132];
  __shared__ __align__(16) float sW[32 * 120];
  const int tid = threadIdx.x;
  const int row0 = blockIdx.x * 128;
  const int tx = tid % 30;
  const int ty = tid / 30;
  const bool comp = tid < 240;
  float4 acc[16];
#pragma unroll
  for (int i = 0; i < 16; ++i) acc[i] = make_float4(0.f, 0.f, 0.f, 0.f);
  const float4* A4 = (const float4*)A;
  const float4* W4 = (const float4*)W;
  const int rload = tid >> 3;
  const int kq = tid & 7;
  for (int k0 = 0; k0 < 256; k0 += 32) {
    __syncthreads();
#pragma unroll
    for (int it = 0; it < 4; ++it) {
      int idx = tid + it * 256;
      if (idx < 960) ((float4*)sW)[idx] = W4[k0 * 30 + idx];
    }
#pragma unroll
    for (int m = 0; m < 4; ++m) {
      int rr = rload + m * 32;
      float4 v = A4[(size_t)(row0 + rr) * 64 + (k0 >> 2) + kq];
      int kk = kq * 4;
      sA[(kk + 0) * 132 + rr] = v.x;
      sA[(kk + 1) * 132 + rr] = v.y;
      sA[(kk + 2) * 132 + rr] = v.z;
      sA[(kk + 3) * 132 + rr] = v.w;
    }
    __syncthreads();
    if (comp) {
#pragma unroll 4
      for (int k = 0; k < 32; ++k) {
        const float4 w = ((const float4*)sW)[k * 30 + tx];
        const float4* a4 = (const float4*)&sA[k * 132 + ty * 16];
        float4 a0 = a4[0], a1 = a4[1], a2 = a4[2], a3 = a4[3];
        float av[16] = {a0.x, a0.y, a0.z, a0.w, a1.x, a1.y, a1.z, a1.w,
                        a2.x, a2.y, a2.z, a2.w, a3.x, a3.y, a3.z, a3.w};
#pragma unroll
        for (int i = 0; i < 16; ++i) {
          acc[i].x = fmaf(av[i], w.x, acc[i].x);
          acc[i].y = fmaf(av[i], w.y, acc[i].y);
          acc[i].z = fmaf(av[i], w.z, acc[i].z);
          acc[i].w = fmaf(av[i], w.w, acc[i].w);
        }
      }
    }
  }
  if (comp) {
    const float4 bv = ((const float4*)bias)[tx];
#pragma unroll
    for (int i = 0; i < 16; ++i) {
      int row = row0 + ty * 16 + i;
      float4 r;
      r.x = acc[i].x + bv.x;
      r.y = acc[i].y + bv.y;
      r.z = acc[i].z + bv.z;
      r.w = acc[i].w + bv.w;
      ((float4*)out)[(size_t)row * 30 + tx] = r;
    }
  }
}

// ---------------- K2: 2-wave segment-pipelined fused scan ----------------
__global__ __launch_bounds__(128, 1)
__attribute__((amdgpu_waves_per_eu(1, 1)))
void scan_kernel(
    const float* __restrict__ pre, const float* __restrict__ enc_W1,
    const float* __restrict__ enc_W2, const float* __restrict__ enc_b2,
    const float* __restrict__ enc_Wd, const float* __restrict__ enc_bd,
    const float* __restrict__ dec_W1, const float* __restrict__ dec_b1,
    const float* __restrict__ dec_W2, const float* __restrict__ dec_b2,
    float* __restrict__ out, float* __restrict__ dec_seq) {
  __shared__ __align__(16) float ring[4][32];  // h1(t) -> slot t&3 (wave0 -> wave1)
  const int tid = threadIdx.x;
  const int wave = tid >> 6;
  const int lane = tid & 63;
  const int blk = blockIdx.x;
  const bool isdec = (blk == BB);
  const int r = lane & 31;
  const bool jo = lane >= 32;
  const int cA = (r < 30) ? (jo ? 30 + r : r) : 0;  // i or j col (idle lanes alias 0)
  const int cB = cA + 60;                           // f or o col
  const float m1 = jo ? 2.0f * L2E : -L2E;
  const float A1 = jo ? -2.0f : 1.0f;
  const float B1 = jo ? 1.0f : 0.0f;
  const float fb = jo ? 0.0f : 1.0f;
  const bool wlane = lane < 30;
  const bool do_dec = isdec && (lane == HH - 1);

  const int cb = (blk < BB) ? blk : 0;  // dec block streams chain0 rows (unused)
  const float* pr = pre + (size_t)cb * TT * GG;

  if (wave == 0) {
    // ================= wave0: layer-1 chain =================
    float wA[30], wB[30];
    const float* W1h = isdec ? (dec_W1 + GG) : (enc_W1 + (size_t)DD * GG);
#pragma unroll
    for (int k = 0; k < 30; ++k) {
      wA[k] = W1h[k * GG + cA];
      wB[k] = W1h[k * GG + cB];
    }
#pragma unroll
    for (int k = 0; k < 30; ++k) asm volatile("" : "+v"(wA[k]), "+v"(wB[k]));
    const float db1A = dec_b1[cA], db1B = dec_b1[cB];

    float sh1[30];  // h1(t-1), uniform (readlane) -> SGPR-resident
#pragma unroll
    for (int k = 0; k < 30; ++k) sh1[k] = 0.f;
    float c1 = 0.f;

    // pre1 prefetch queue: rows (2g,2g+1) current, (2g+2,2g+3) next.
    float qA0 = pr[0 * GG + cA], qB0 = pr[0 * GG + cB];
    float qA1 = pr[1 * GG + cA], qB1 = pr[1 * GG + cB];
    float rA0 = pr[2 * GG + cA], rB0 = pr[2 * GG + cB];
    float rA1 = pr[3 * GG + cA], rB1 = pr[3 * GG + cB];

    auto l1step = [&](int t, float pA, float pB) {
      float aA = isdec ? db1A : pA;
      float aB = isdec ? db1B : pB;
#pragma unroll
      for (int k = 0; k < 30; ++k) {
        aA = fmaf(sh1[k], wA[k], aA);
        aB = fmaf(sh1[k], wB[k], aB);
      }
      float t1 = fast_rcp(1.0f + fast_exp2(aA * m1));
      float p1 = fmaf(t1, A1, B1);                              // sigm(i)/tanh(j)
      float p2 = fast_rcp(1.0f + fast_exp2((aB + fb) * -L2E));  // sigm(f+1)/sigm(o)
      float jv = __shfl_xor(p1, 32, 64);
      float ov = __shfl_xor(p2, 32, 64);
      c1 = fmaf(c1, p2, p1 * jv);
      float hv = tanh_(c1) * ov;
      if (wlane) ring[t & 3][lane] = hv;  // cross-wave handoff
#pragma unroll
      for (int k = 0; k < 30; ++k) sh1[k] = bcastf(hv, k);  // self-broadcast
    };

    for (int g = 0; g < TT / 2; ++g) {
      int tp0 = (2 * g + 4 < TT) ? 2 * g + 4 : 0;  // tail loads discarded
      int tp1 = (2 * g + 5 < TT) ? 2 * g + 5 : 0;
      float fA0 = pr[(size_t)tp0 * GG + cA], fB0 = pr[(size_t)tp0 * GG + cB];
      float fA1 = pr[(size_t)tp1 * GG + cA], fB1 = pr[(size_t)tp1 * GG + cB];
      l1step(2 * g, qA0, qB0);
      l1step(2 * g + 1, qA1, qB1);
      qA0 = rA0; qB0 = rB0; qA1 = rA1; qB1 = rB1;
      rA0 = fA0; rB0 = fB0; rA1 = fA1; rB1 = fB1;
      // lgkmcnt(0): own LDS writes visible; NO vmcnt drain (prefetch in flight)
      asm volatile("s_waitcnt lgkmcnt(0)\n\ts_barrier" ::: "memory");
    }
  } else {
    // ================= wave1: layer-2 chain =================
    float wA[60], wB[60];  // W2 rows 0..29 = h1 inputs, 30..59 = h2 inputs
    const float* W2 = isdec ? dec_W2 : enc_W2;
#pragma unroll
    for (int k = 0; k < 60; ++k) {
      wA[k] = W2[k * GG + cA];
      wB[k] = W2[k * GG + cB];
    }
#pragma unroll
    for (int k = 0; k < 60; ++k) asm volatile("" : "+v"(wA[k]), "+v"(wB[k]));
    const float* b2p = isdec ? dec_b2 : enc_b2;
    const float b2A = b2p[cA], b2B = b2p[cB];

    float sh2[30];  // h2(t-1), uniform -> SGPR-resident
#pragma unroll
    for (int k = 0; k < 30; ++k) sh2[k] = 0.f;
    float c2 = 0.f;

    auto l2step = [&](int t) {
      f32x4 h1a[8];  // h1(t) from ring (written by wave0 last segment)
#pragma unroll
      for (int u = 0; u < 8; ++u) h1a[u] = ((const f32x4*)&ring[t & 3][0])[u];
      float aA = b2A, aB = b2B;
#pragma unroll
      for (int k = 0; k < 30; ++k) {
        float hk = h1a[k >> 2][k & 3];
        aA = fmaf(hk, wA[k], aA);
        aB = fmaf(hk, wB[k], aB);
      }
#pragma unroll
      for (int k = 0; k < 30; ++k) {
        aA = fmaf(sh2[k], wA[30 + k], aA);
        aB = fmaf(sh2[k], wB[30 + k], aB);
      }
      float t1 = fast_rcp(1.0f + fast_exp2(aA * m1));
      float p1 = fmaf(t1, A1, B1);
      float p2 = fast_rcp(1.0f + fast_exp2((aB + fb) * -L2E));
      float jv = __shfl_xor(p1, 32, 64);
      float ov = __shfl_xor(p2, 32, 64);
      c2 = fmaf(c2, p2, p1 * jv);
      float hv = tanh_(c2) * ov;
      if (do_dec) dec_seq[t] = hv;
#pragma unroll
      for (int k = 0; k < 30; ++k) sh2[k] = bcastf(hv, k);  // self-broadcast
    };

    for (int g = 0; g < TT / 2; ++g) {
      if (g > 0) {
        l2step(2 * g - 2);
        l2step(2 * g - 1);
      }
      asm volatile("s_waitcnt lgkmcnt(0)\n\ts_barrier" ::: "memory");
    }
    // tail: ring slots 2,3 written in final segment, visible after last barrier
    l2step(TT - 2);
    l2step(TT - 1);
    if (!isdec) {
      // latent = tanh(h2(T-1) @ enc_Wd + enc_bd); h2(T-1) lives in sh2
      const int jc = (lane < 5) ? lane : 0;
      float a = enc_bd[jc];
#pragma unroll
      for (int k = 0; k < 30; ++k) a = fmaf(sh2[k], enc_Wd[k * 5 + jc], a);
      if (lane < 5) out[BB * TT + blk * 5 + lane] = tanh_(a);
    }
  }
}

// ---------------- K3: broadcast decoder chain to all batch rows ----------------
__global__ __launch_bounds__(256) void bcast_kernel(const float* __restrict__ dec_seq,
                                                    float* __restrict__ out) {
  int i4 = blockIdx.x * 256 + threadIdx.x;  // 32768 float4s
  ((float4*)out)[i4] = ((const float4*)dec_seq)[i4 & (TT / 4 - 1)];
}

extern "C" void kernel_launch(void* const* d_in, const int* in_sizes, int n_in,
                              void* d_out, int out_size, void* d_ws, size_t ws_size,
                              hipStream_t stream) {
  const float* seq = (const float*)d_in[0];
  const float* enc_W1 = (const float*)d_in[1];
  const float* enc_b1 = (const float*)d_in[2];
  const float* enc_W2 = (const float*)d_in[3];
  const float* enc_b2 = (const float*)d_in[4];
  const float* enc_Wd = (const float*)d_in[5];
  const float* enc_bd = (const float*)d_in[6];
  // d_in[7] dec_Wd, d_in[8] dec_bd: dead code in reference (vec2 unused)
  const float* dec_W1 = (const float*)d_in[9];
  const float* dec_b1 = (const float*)d_in[10];
  const float* dec_W2 = (const float*)d_in[11];
  const float* dec_b2 = (const float*)d_in[12];
  float* out = (float*)d_out;
  float* pre = (float*)d_ws;         // 62.9 MB
  float* dec_seq = pre + PRE_ELEMS;  // 8 KB

  gemm_pre<<<dim3(1024), dim3(256), 0, stream>>>(seq, enc_W1, enc_b1, pre);
  scan_kernel<<<dim3(65), dim3(128), 0, stream>>>(pre, enc_W1, enc_W2, enc_b2,
                                                  enc_Wd, enc_bd, dec_W1, dec_b1,
                                                  dec_W2, dec_b2, out, dec_seq);
  bcast_kernel<<<dim3(128), dim3(256), 0, stream>>>(dec_seq, out);
}